// Round 15
// baseline (254.147 us; speedup 1.0000x reference)
//
#include <hip/hip_runtime.h>
#include <cstdint>

#define S_LEN   2048
#define D_MODEL 1024
#define NHEAD   16
#define DHEAD   64
#define BATCH   2
#define M_ROWS  (BATCH * S_LEN)   // 4096

typedef __attribute__((ext_vector_type(8))) short bf16x8;
typedef __attribute__((ext_vector_type(4))) float f32x4;

__device__ __forceinline__ unsigned short f2bf(float f) {
    union { float f; uint32_t u; } v; v.f = f;
    uint32_t u = v.u;
    return (unsigned short)((u + 0x7FFFu + ((u >> 16) & 1u)) >> 16);
}

__device__ __forceinline__ float bf2f(uint32_t u16) {
    union { uint32_t u; float f; } x; x.u = u16 << 16; return x.f;
}

__device__ __forceinline__ uint32_t cvt_pk_bf16(float a, float b) {
    uint32_t r;
    asm("v_cvt_pk_bf16_f32 %0, %1, %2" : "=v"(r) : "v"(a), "v"(b));
    return r;
}

__device__ __forceinline__ void gload_lds16(const void* g, void* l) {
    __builtin_amdgcn_global_load_lds(
        (const __attribute__((address_space(1))) void*)g,
        (__attribute__((address_space(3))) void*)l, 16, 0, 0);
}

// ---------------- fused f32 -> bf16 convert ----------------
struct CvtArgs {
    const float* src[7];
    unsigned short* dst[7];
    int n4[7];
};
__global__ __launch_bounds__(256) void cvt_all(CvtArgs a) {
    const int which = blockIdx.y;
    const int t = blockIdx.x * 256 + threadIdx.x;
    if (t >= a.n4[which]) return;
    f32x4 v = reinterpret_cast<const f32x4*>(a.src[which])[t];
    uint2 o;
    o.x = cvt_pk_bf16(v[0], v[1]);
    o.y = cvt_pk_bf16(v[2], v[3]);
    reinterpret_cast<uint2*>(a.dst[which])[t] = o;
}

// ---------------- GEMM body: C = A @ Bw^T + bias (K=1024) ----------------
template<int MODE>
__device__ __forceinline__ void gemm_body(
    unsigned short* lA, unsigned short* lB,
    const unsigned short* __restrict__ A,
    const unsigned short* __restrict__ Bw,
    const float* __restrict__ bias,
    void* __restrict__ Cout,
    int bx, int by, float prescale)
{
    constexpr int K = 1024;
    const int tid  = threadIdx.x;
    const int lane = tid & 63;
    const int w    = tid >> 6;
    const int wr   = w >> 1, wc = w & 1;
    const int g    = lane >> 4, r16 = lane & 15;
    const int brow = by * 128;
    const int bcol = bx * 128;

    f32x4 acc[4][4];
#pragma unroll
    for (int i = 0; i < 4; ++i)
#pragma unroll
        for (int j = 0; j < 4; ++j) acc[i][j] = (f32x4){0.f, 0.f, 0.f, 0.f};

    const int rA0 = tid >> 2;
    const int cc  = (tid & 3) * 8;

    for (int kk = 0; kk < K; kk += 32) {
#pragma unroll
        for (int it = 0; it < 2; ++it) {
            int r = it * 64 + rA0;
            gload_lds16(A  + (size_t)(brow + r) * K + kk + cc, &lA[r * 32 + cc]);
            gload_lds16(Bw + (size_t)(bcol + r) * K + kk + cc, &lB[r * 32 + cc]);
        }
        __syncthreads();
        bf16x8 af[4], bfr[4];
#pragma unroll
        for (int i = 0; i < 4; ++i)
            af[i] = *reinterpret_cast<const bf16x8*>(&lA[(wr * 64 + i * 16 + r16) * 32 + g * 8]);
#pragma unroll
        for (int j = 0; j < 4; ++j)
            bfr[j] = *reinterpret_cast<const bf16x8*>(&lB[(wc * 64 + j * 16 + r16) * 32 + g * 8]);
#pragma unroll
        for (int i = 0; i < 4; ++i)
#pragma unroll
            for (int j = 0; j < 4; ++j)
                acc[i][j] = __builtin_amdgcn_mfma_f32_16x16x32_bf16(af[i], bfr[j], acc[i][j], 0, 0, 0);
        __syncthreads();
    }

#pragma unroll
    for (int i = 0; i < 4; ++i) {
#pragma unroll
        for (int j = 0; j < 4; ++j) {
            const int n = bcol + wc * 64 + j * 16 + r16;
#pragma unroll
            for (int rr = 0; rr < 4; ++rr) {
                const int m = brow + wr * 64 + i * 16 + g * 4 + rr;
                float val = acc[i][j][rr];
                if (MODE == 0) {
                    val = (val + bias[n]) * prescale;
                    int b = m >> 11, s = m & 2047;
                    int h = n >> 6,  d = n & 63;
                    ((unsigned short*)Cout)[(((size_t)(b * NHEAD + h)) * S_LEN + s) * DHEAD + d] = f2bf(val);
                } else if (MODE == 1) {
                    val += bias[m];
                    int h = m >> 6,  d = m & 63;
                    int b = n >> 11, s = n & 2047;
                    ((unsigned short*)Cout)[(((size_t)(b * NHEAD + h)) * DHEAD + d) * S_LEN + s] = f2bf(val);
                } else {
                    val += bias[n];
                    ((float*)Cout)[(size_t)m * D_MODEL + n] = val;
                }
            }
        }
    }
}

// ---------------- merged Q/K/V projections (768 blocks) ----------------
__global__ __launch_bounds__(256) void proj_all(
    const unsigned short* qb, const unsigned short* wqb, const float* wq_b, unsigned short* Qhp,
    const unsigned short* kb, const unsigned short* wkb, const float* wk_b, unsigned short* Khp,
    const unsigned short* vb, const unsigned short* wvb, const float* wv_b, unsigned short* Vtp,
    float qscale)
{
    __shared__ unsigned short lA[128 * 32];
    __shared__ unsigned short lB[128 * 32];
    const int bid = blockIdx.x;
    const int z = bid >> 8, t = bid & 255;
    if (z == 0)
        gemm_body<0>(lA, lB, qb, wqb, wq_b, Qhp, t & 7, t >> 3, qscale);
    else if (z == 1)
        gemm_body<0>(lA, lB, kb, wkb, wk_b, Khp, t & 7, t >> 3, 1.0f);
    else
        gemm_body<1>(lA, lB, wvb, vb, wv_b, Vtp, t & 31, t >> 5, 1.0f);
}

// ---------------- kernel A: flash ctx + stats, LDS-staged K/V (r10) ----------
__global__ __launch_bounds__(512, 2) void attn_ctx_kernel(
    const unsigned short* __restrict__ Qh,
    const unsigned short* __restrict__ Kh,
    const unsigned short* __restrict__ Vt,
    float* __restrict__ stats,
    unsigned short* __restrict__ ctx)
{
    __shared__ unsigned short ldsK[2][64 * 64];   // 16 KB
    __shared__ unsigned short ldsV[2][64 * 64];   // 16 KB
    __shared__ unsigned short pS[8][16 * 72];     // 18 KB

    const int tid  = threadIdx.x;
    const int lane = tid & 63;
    const int w    = tid >> 6;          // 0..7
    const int g    = lane >> 4, r16 = lane & 15;
    const int wg   = w & 3;             // row-group within qtile
    const int grp  = w >> 2;            // 0 = heavy, 1 = light

    const int lid = blockIdx.x;         // 0..255 ; lid%8 = XCD
    const int xcd = lid & 7;
    const int rest = lid >> 3;          // 0..31
    const int bh  = xcd * 4 + (rest >> 3);
    const int ii  = rest & 7;           // 0..7
    const int b   = bh >> 4, h = bh & 15;

    const unsigned short* Kp = Kh + (size_t)bh * S_LEN * DHEAD;
    const unsigned short* Vp = Vt + (size_t)bh * DHEAD * S_LEN;

    const int srow = tid >> 3;              // staging row (0..63)
    const int scol = (tid & 7) * 16;        // staging byte col
    const int sswz = scol ^ ((srow & 7) << 4);
    const int rsw  = (r16 & 7) << 4;        // read-side XOR

    unsigned short* pl = pS[w];

    for (int pp = 0; pp < 2; ++pp) {
        const int p  = pp == 0 ? ii : 15 - ii;
        const int qh = 16 + p;              // heavy qtile
        const int ql = 15 - p;              // light qtile
        const int qtile = grp == 0 ? qh : ql;
        const int qw    = qtile * 64 + wg * 16;
        const int qrel  = wg * 16 + r16;
        const int myN   = qtile;            // compute while t <= myN

        const unsigned short* Qp = Qh + ((size_t)bh * S_LEN + qw) * DHEAD;
        bf16x8 qf[2];
#pragma unroll
        for (int d2 = 0; d2 < 2; ++d2)
            qf[d2] = *reinterpret_cast<const bf16x8*>(Qp + (size_t)r16 * DHEAD + d2 * 32 + g * 8);

        auto stageKV = [&](int kt, int buf) {
            gload_lds16((const char*)Kp + (size_t)(kt * 64 + srow) * 128 + sswz,
                        (char*)ldsK[buf] + tid * 16);
            gload_lds16((const char*)Vp + (size_t)srow * (S_LEN * 2) + (size_t)kt * 128 + sswz,
                        (char*)ldsV[buf] + tid * 16);
        };

        float l_run = 0.f;
        f32x4 of[4];
#pragma unroll
        for (int nt = 0; nt < 4; ++nt) of[nt] = (f32x4){0, 0, 0, 0};

        int buf = 0;
        stageKV(0, 0);
        __syncthreads();
        for (int t = 0; t <= qh; ++t) {
            if (t < qh) stageKV(t + 1, buf ^ 1);
            if (t <= myN) {
                const bool masked = (t == myN);
                bf16x8 kf[8];
#pragma unroll
                for (int d2 = 0; d2 < 2; ++d2)
#pragma unroll
                    for (int nt = 0; nt < 4; ++nt)
                        kf[d2 * 4 + nt] = *reinterpret_cast<const bf16x8*>(
                            (const char*)ldsK[buf] + (nt * 16 + r16) * 128 + ((d2 * 64 + g * 16) ^ rsw));
                f32x4 sf[4];
#pragma unroll
                for (int nt = 0; nt < 4; ++nt) sf[nt] = (f32x4){0, 0, 0, 0};
                __builtin_amdgcn_s_setprio(1);
#pragma unroll
                for (int d2 = 0; d2 < 2; ++d2)
#pragma unroll
                    for (int nt = 0; nt < 4; ++nt)
                        sf[nt] = __builtin_amdgcn_mfma_f32_16x16x32_bf16(kf[d2 * 4 + nt], qf[d2], sf[nt], 0, 0, 0);
                __builtin_amdgcn_s_setprio(0);
                float sum = 0.f;
#pragma unroll
                for (int nt = 0; nt < 4; ++nt)
#pragma unroll
                    for (int rr = 0; rr < 4; ++rr) {
                        float e = __builtin_amdgcn_exp2f(sf[nt][rr]);   // unnormalized
                        if (masked && (nt * 16 + g * 4 + rr > qrel)) e = 0.f;
                        sf[nt][rr] = e;
                        sum += e;
                    }
                l_run += sum;
#pragma unroll
                for (int nt = 0; nt < 4; ++nt) {
                    uint2 pk2;
                    pk2.x = cvt_pk_bf16(sf[nt][0], sf[nt][1]);
                    pk2.y = cvt_pk_bf16(sf[nt][2], sf[nt][3]);
                    *reinterpret_cast<uint2*>(&pl[r16 * 72 + nt * 16 + g * 4]) = pk2;
                }
                __builtin_amdgcn_wave_barrier();
                __builtin_amdgcn_s_setprio(1);
#pragma unroll
                for (int kh = 0; kh < 2; ++kh) {
                    bf16x8 pa = *reinterpret_cast<const bf16x8*>(&pl[r16 * 72 + kh * 32 + g * 8]);
#pragma unroll
                    for (int nt = 0; nt < 4; ++nt) {
                        bf16x8 vf = *reinterpret_cast<const bf16x8*>(
                            (const char*)ldsV[buf] + (nt * 16 + r16) * 128 + ((kh * 64 + g * 16) ^ rsw));
                        of[nt] = __builtin_amdgcn_mfma_f32_16x16x32_bf16(vf, pa, of[nt], 0, 0, 0);
                    }
                }
                __builtin_amdgcn_s_setprio(0);
            }
            __syncthreads();   // publishes buf^1, guards buf overwrite
            buf ^= 1;
        }

        float lx = l_run;
        lx += __shfl_xor(lx, 16);
        lx += __shfl_xor(lx, 32);
        const float mprime = __builtin_amdgcn_logf(lx);   // log2(l)
        if (lane < 16)
            stats[(size_t)bh * S_LEN + qw + r16] = mprime;

        const float inv = 1.f / lx;
        const size_t crow = ((size_t)b * S_LEN + qw + r16) * D_MODEL + h * DHEAD;
#pragma unroll
        for (int nt = 0; nt < 4; ++nt) {
            uint2 pk2;
            pk2.x = cvt_pk_bf16(of[nt][0] * inv, of[nt][1] * inv);
            pk2.y = cvt_pk_bf16(of[nt][2] * inv, of[nt][3] * inv);
            *reinterpret_cast<uint2*>(&ctx[crow + nt * 16 + g * 4]) = pk2;
        }
        __syncthreads();   // pass boundary: LDS reuse safe
    }
}

// ---------------- fused output ------------------------------------------------
// Blocks 0..255: gemm_o. Blocks 256..767: zero-band blocks — fill-like long
// row sweeps (1KB/instr contiguous, up to 7.9KB/row) over the upper triangle.
// Blocks 768..9471: 64x128 P-chunks (r13 structure, mirror zeros removed) —
// purely band-local nt stores.
__global__ __launch_bounds__(256) void fused_out(
    const unsigned short* __restrict__ ctx,
    const unsigned short* __restrict__ wob,
    const float* __restrict__ wo_b,
    float* __restrict__ yout,
    const unsigned short* __restrict__ Qh,
    const unsigned short* __restrict__ Kh,
    const float* __restrict__ stats,
    float* __restrict__ attn_out)
{
    __shared__ unsigned short lds[64 * 136 + 64];   // 17.5 KB (gemm uses 16 KB)
    const int bid = blockIdx.x;
    if (bid < 256) {
        gemm_body<2>(lds, lds + 128 * 32, ctx, wob, wo_b, yout, bid & 7, bid >> 3, 1.0f);
        return;
    }

    const int tid  = threadIdx.x;
    const int lane = tid & 63;
    const int w    = tid >> 6;          // 0..3
    const f32x4 z4 = (f32x4){0.f, 0.f, 0.f, 0.f};

    if (bid < 768) {
        // ---- zero-band block: (bh, p) -> bands qt=p and qt=31-p ----
        const int zb  = bid - 256;      // 0..511
        const int xcd = zb & 7;
        const int rest = zb >> 3;       // 0..63
        const int bh  = xcd * 4 + (rest >> 4);
        const int p   = rest & 15;
#pragma unroll
        for (int s = 0; s < 2; ++s) {
            const int qt = (s == 0) ? p : 31 - p;
            const int z0 = (qt + 1) * 64;
            // wave w: rows w*16 .. w*16+15; per row: 1KB/instr contiguous sweep
            for (int r = 0; r < 16; ++r) {
                float* dst = attn_out + (size_t)bh * S_LEN * S_LEN
                           + (size_t)(qt * 64 + w * 16 + r) * S_LEN;
                for (int c = z0 + lane * 4; c < S_LEN; c += 256)
                    __builtin_nontemporal_store(z4, reinterpret_cast<f32x4*>(dst + c));
            }
        }
        return;
    }

    // ---- P chunk (64 q-rows x 128 k-cols), band-local stores only ----
    const int g    = lane >> 4, r16 = lane & 15;

    const int pid = bid - 768;          // 0..8703
    const int xcd = pid & 7;
    const int cid = pid >> 3;           // 0..1087
    const int bh  = xcd * 4 + cid / 272;
    const int t   = cid % 272;
    int m = (int)((sqrtf(4.f * t + 1.f) - 1.f) * 0.5f);
    while (m * (m + 1) > t) --m;
    while ((m + 1) * (m + 2) <= t) ++m;
    int qt, c2;
    if (t < (m + 1) * (m + 1)) { qt = 2 * m;     c2 = t - m * (m + 1); }
    else                       { qt = 2 * m + 1; c2 = t - (m + 1) * (m + 1); }

    float* abase = attn_out + (size_t)bh * S_LEN * S_LEN;
    const int qw   = qt * 64 + w * 16;
    const int qrel = w * 16 + r16;
    const unsigned short* Qp = Qh + ((size_t)bh * S_LEN + qw) * DHEAD;
    const unsigned short* Kp = Kh + (size_t)bh * S_LEN * DHEAD;

    bf16x8 qf[2];
#pragma unroll
    for (int d2 = 0; d2 < 2; ++d2)
        qf[d2] = *reinterpret_cast<const bf16x8*>(Qp + (size_t)r16 * DHEAD + d2 * 32 + g * 8);
    const float mpr = stats[(size_t)bh * S_LEN + qw + r16];

    unsigned short* plw = lds + w * (16 * 136);

#pragma unroll
    for (int kl = 0; kl < 2; ++kl) {
        const int kt = 2 * c2 + kl;
        if (kt > qt) {
            const uint2 zz = {0u, 0u};
#pragma unroll
            for (int nt = 0; nt < 4; ++nt)
                *reinterpret_cast<uint2*>(&plw[r16 * 136 + kl * 64 + nt * 16 + g * 4]) = zz;
            continue;
        }
        bf16x8 kf[8];
#pragma unroll
        for (int d2 = 0; d2 < 2; ++d2)
#pragma unroll
            for (int nt = 0; nt < 4; ++nt)
                kf[d2 * 4 + nt] = *reinterpret_cast<const bf16x8*>(
                    Kp + (size_t)(kt * 64 + nt * 16 + r16) * DHEAD + d2 * 32 + g * 8);
        f32x4 sf[4];
#pragma unroll
        for (int nt = 0; nt < 4; ++nt) sf[nt] = (f32x4){0, 0, 0, 0};
        __builtin_amdgcn_s_setprio(1);
#pragma unroll
        for (int d2 = 0; d2 < 2; ++d2)
#pragma unroll
            for (int nt = 0; nt < 4; ++nt)
                sf[nt] = __builtin_amdgcn_mfma_f32_16x16x32_bf16(kf[d2 * 4 + nt], qf[d2], sf[nt], 0, 0, 0);
        __builtin_amdgcn_s_setprio(0);
        const bool masked = (kt == qt);
#pragma unroll
        for (int nt = 0; nt < 4; ++nt) {
#pragma unroll
            for (int rr = 0; rr < 4; ++rr) {
                float p = __builtin_amdgcn_exp2f(sf[nt][rr] - mpr);
                if (masked && (nt * 16 + g * 4 + rr > qrel)) p = 0.f;
                sf[nt][rr] = p;
            }
            uint2 pk2;
            pk2.x = cvt_pk_bf16(sf[nt][0], sf[nt][1]);
            pk2.y = cvt_pk_bf16(sf[nt][2], sf[nt][3]);
            *reinterpret_cast<uint2*>(&plw[r16 * 136 + kl * 64 + nt * 16 + g * 4]) = pk2;
        }
    }
    __builtin_amdgcn_wave_barrier();

    // readback: 8 insts x (2 rows x 512B), nt stores
    float* dst0 = abase + (size_t)qw * S_LEN + c2 * 128;
    const int rsub = lane >> 5;             // 0..1
    const int cc2  = (lane & 31) * 4;       // 0..124
#pragma unroll
    for (int i = 0; i < 8; ++i) {
        const int r = i * 2 + rsub;
        uint2 d = *reinterpret_cast<const uint2*>(&plw[r * 136 + cc2]);
        f32x4 o;
        o[0] = bf2f(d.x & 0xffffu);
        o[1] = bf2f(d.x >> 16);
        o[2] = bf2f(d.y & 0xffffu);
        o[3] = bf2f(d.y >> 16);
        __builtin_nontemporal_store(o, reinterpret_cast<f32x4*>(dst0 + (size_t)r * S_LEN + cc2));
    }
}

extern "C" void kernel_launch(void* const* d_in, const int* in_sizes, int n_in,
                              void* d_out, int out_size, void* d_ws, size_t ws_size,
                              hipStream_t stream)
{
    const float* q    = (const float*)d_in[0];
    const float* k    = (const float*)d_in[1];
    const float* v    = (const float*)d_in[2];
    const float* wq_w = (const float*)d_in[4];
    const float* wq_b = (const float*)d_in[5];
    const float* wk_w = (const float*)d_in[6];
    const float* wk_b = (const float*)d_in[7];
    const float* wv_w = (const float*)d_in[8];
    const float* wv_b = (const float*)d_in[9];
    const float* wo_w = (const float*)d_in[10];
    const float* wo_b = (const float*)d_in[11];

    char* ws = (char*)d_ws;
    const size_t MB = 1024 * 1024;
    unsigned short* qb  = (unsigned short*)(ws + 0 * MB);
    unsigned short* kb  = (unsigned short*)(ws + 8 * MB);
    unsigned short* vb  = (unsigned short*)(ws + 16 * MB);
    unsigned short* wqb = (unsigned short*)(ws + 24 * MB);
    unsigned short* wkb = (unsigned short*)(ws + 26 * MB);
    unsigned short* wvb = (unsigned short*)(ws + 28 * MB);
    unsigned short* wob = (unsigned short*)(ws + 30 * MB);
    unsigned short* Qhp = (unsigned short*)(ws + 32 * MB);
    unsigned short* Khp = (unsigned short*)(ws + 40 * MB);
    unsigned short* Vtp = (unsigned short*)(ws + 48 * MB);
    unsigned short* ctx = (unsigned short*)(ws + 56 * MB);
    // stats overlays qb (dead after projections; rewritten every launch)
    float* stats = (float*)(ws + 0 * MB);

    float* yout = (float*)d_out;
    float* attn = yout + (size_t)M_ROWS * D_MODEL;

    CvtArgs ca;
    ca.src[0] = q;    ca.dst[0] = qb;  ca.n4[0] = M_ROWS * D_MODEL / 4;
    ca.src[1] = k;    ca.dst[1] = kb;  ca.n4[1] = M_ROWS * D_MODEL / 4;
    ca.src[2] = v;    ca.dst[2] = vb;  ca.n4[2] = M_ROWS * D_MODEL / 4;
    ca.src[3] = wq_w; ca.dst[3] = wqb; ca.n4[3] = D_MODEL * D_MODEL / 4;
    ca.src[4] = wk_w; ca.dst[4] = wkb; ca.n4[4] = D_MODEL * D_MODEL / 4;
    ca.src[5] = wv_w; ca.dst[5] = wvb; ca.n4[5] = D_MODEL * D_MODEL / 4;
    ca.src[6] = wo_w; ca.dst[6] = wob; ca.n4[6] = D_MODEL * D_MODEL / 4;
    cvt_all<<<dim3((M_ROWS * D_MODEL / 4 + 255) / 256, 7), dim3(256), 0, stream>>>(ca);

    const float qscale = 0.125f * 1.44269504088896340736f;  // fold scale*log2(e) into Q
    proj_all<<<dim3(768), dim3(256), 0, stream>>>(
        qb, wqb, wq_b, Qhp,
        kb, wkb, wk_b, Khp,
        vb, wvb, wv_b, Vtp, qscale);

    attn_ctx_kernel<<<dim3(256), dim3(512), 0, stream>>>(Qhp, Khp, Vtp, stats, ctx);

    fused_out<<<dim3(256 + 512 + 8704), dim3(256), 0, stream>>>(
        ctx, wob, wo_b, yout, Qhp, Khp, stats, attn);
}

// Round 16
// 232.309 us; speedup vs baseline: 1.0940x; 1.0940x over previous
//
#include <hip/hip_runtime.h>
#include <cstdint>

#define S_LEN   2048
#define D_MODEL 1024
#define NHEAD   16
#define DHEAD   64
#define BATCH   2
#define M_ROWS  (BATCH * S_LEN)   // 4096

typedef __attribute__((ext_vector_type(8))) short bf16x8;
typedef __attribute__((ext_vector_type(4))) float f32x4;

__device__ __forceinline__ unsigned short f2bf(float f) {
    union { float f; uint32_t u; } v; v.f = f;
    uint32_t u = v.u;
    return (unsigned short)((u + 0x7FFFu + ((u >> 16) & 1u)) >> 16);
}

__device__ __forceinline__ float bf2f(uint32_t u16) {
    union { uint32_t u; float f; } x; x.u = u16 << 16; return x.f;
}

__device__ __forceinline__ uint32_t cvt_pk_bf16(float a, float b) {
    uint32_t r;
    asm("v_cvt_pk_bf16_f32 %0, %1, %2" : "=v"(r) : "v"(a), "v"(b));
    return r;
}

__device__ __forceinline__ void gload_lds16(const void* g, void* l) {
    __builtin_amdgcn_global_load_lds(
        (const __attribute__((address_space(1))) void*)g,
        (__attribute__((address_space(3))) void*)l, 16, 0, 0);
}

// ---------------- GEMM body: C = A @ Bw^T + bias (K=1024) ----------------
// AF32/BF32: operand is f32 in global; convert to bf16 during reg-staging.
// MODE 0: out bf16 head-major [BH][S][64], scaled.  MODE 1: out bf16 V^T
// [BH][64][S] (bias[m]).  MODE 2: out f32 [M][1024].
template<int MODE, int AF32, int BF32>
__device__ __forceinline__ void gemm_body(
    unsigned short* lA, unsigned short* lB,
    const void* __restrict__ Av,
    const void* __restrict__ Bv,
    const float* __restrict__ bias,
    void* __restrict__ Cout,
    int bx, int by, float prescale)
{
    constexpr int K = 1024;
    const int tid  = threadIdx.x;
    const int lane = tid & 63;
    const int w    = tid >> 6;
    const int wr   = w >> 1, wc = w & 1;
    const int g    = lane >> 4, r16 = lane & 15;
    const int brow = by * 128;
    const int bcol = bx * 128;

    f32x4 acc[4][4];
#pragma unroll
    for (int i = 0; i < 4; ++i)
#pragma unroll
        for (int j = 0; j < 4; ++j) acc[i][j] = (f32x4){0.f, 0.f, 0.f, 0.f};

    const int rA0 = tid >> 2;
    const int cc  = (tid & 3) * 8;

    for (int kk = 0; kk < K; kk += 32) {
#pragma unroll
        for (int it = 0; it < 2; ++it) {
            const int r = it * 64 + rA0;
            if (AF32) {
                const float* src = (const float*)Av + (size_t)(brow + r) * K + kk + cc;
                float4 v0 = *reinterpret_cast<const float4*>(src);
                float4 v1 = *reinterpret_cast<const float4*>(src + 4);
                uint4 pk;
                pk.x = cvt_pk_bf16(v0.x, v0.y);
                pk.y = cvt_pk_bf16(v0.z, v0.w);
                pk.z = cvt_pk_bf16(v1.x, v1.y);
                pk.w = cvt_pk_bf16(v1.z, v1.w);
                *reinterpret_cast<uint4*>(&lA[r * 32 + cc]) = pk;
            } else {
                gload_lds16((const unsigned short*)Av + (size_t)(brow + r) * K + kk + cc,
                            &lA[r * 32 + cc]);
            }
            if (BF32) {
                const float* src = (const float*)Bv + (size_t)(bcol + r) * K + kk + cc;
                float4 v0 = *reinterpret_cast<const float4*>(src);
                float4 v1 = *reinterpret_cast<const float4*>(src + 4);
                uint4 pk;
                pk.x = cvt_pk_bf16(v0.x, v0.y);
                pk.y = cvt_pk_bf16(v0.z, v0.w);
                pk.z = cvt_pk_bf16(v1.x, v1.y);
                pk.w = cvt_pk_bf16(v1.z, v1.w);
                *reinterpret_cast<uint4*>(&lB[r * 32 + cc]) = pk;
            } else {
                gload_lds16((const unsigned short*)Bv + (size_t)(bcol + r) * K + kk + cc,
                            &lB[r * 32 + cc]);
            }
        }
        __syncthreads();
        bf16x8 af[4], bfr[4];
#pragma unroll
        for (int i = 0; i < 4; ++i)
            af[i] = *reinterpret_cast<const bf16x8*>(&lA[(wr * 64 + i * 16 + r16) * 32 + g * 8]);
#pragma unroll
        for (int j = 0; j < 4; ++j)
            bfr[j] = *reinterpret_cast<const bf16x8*>(&lB[(wc * 64 + j * 16 + r16) * 32 + g * 8]);
#pragma unroll
        for (int i = 0; i < 4; ++i)
#pragma unroll
            for (int j = 0; j < 4; ++j)
                acc[i][j] = __builtin_amdgcn_mfma_f32_16x16x32_bf16(af[i], bfr[j], acc[i][j], 0, 0, 0);
        __syncthreads();
    }

#pragma unroll
    for (int i = 0; i < 4; ++i) {
#pragma unroll
        for (int j = 0; j < 4; ++j) {
            const int n = bcol + wc * 64 + j * 16 + r16;
#pragma unroll
            for (int rr = 0; rr < 4; ++rr) {
                const int m = brow + wr * 64 + i * 16 + g * 4 + rr;
                float val = acc[i][j][rr];
                if (MODE == 0) {
                    val = (val + bias[n]) * prescale;
                    int b = m >> 11, s = m & 2047;
                    int h = n >> 6,  d = n & 63;
                    ((unsigned short*)Cout)[(((size_t)(b * NHEAD + h)) * S_LEN + s) * DHEAD + d] = f2bf(val);
                } else if (MODE == 1) {
                    val += bias[m];
                    int h = m >> 6,  d = m & 63;
                    int b = n >> 11, s = n & 2047;
                    ((unsigned short*)Cout)[(((size_t)(b * NHEAD + h)) * DHEAD + d) * S_LEN + s] = f2bf(val);
                } else {
                    val += bias[n];
                    ((float*)Cout)[(size_t)m * D_MODEL + n] = val;
                }
            }
        }
    }
}

// ---------------- merged Q/K/V projections, f32 inputs (768 blocks) -----------
__global__ __launch_bounds__(256) void proj_all(
    const float* q,  const float* wq_w, const float* wq_b, unsigned short* Qhp,
    const float* k,  const float* wk_w, const float* wk_b, unsigned short* Khp,
    const float* v,  const float* wv_w, const float* wv_b, unsigned short* Vtp,
    float qscale)
{
    __shared__ unsigned short lA[128 * 32];
    __shared__ unsigned short lB[128 * 32];
    const int bid = blockIdx.x;
    const int z = bid >> 8, t = bid & 255;
    if (z == 0)
        gemm_body<0, 1, 1>(lA, lB, q, wq_w, wq_b, Qhp, t & 7, t >> 3, qscale);
    else if (z == 1)
        gemm_body<0, 1, 1>(lA, lB, k, wk_w, wk_b, Khp, t & 7, t >> 3, 1.0f);
    else
        gemm_body<1, 1, 1>(lA, lB, wv_w, v, wv_b, Vtp, t & 31, t >> 5, 1.0f);
}

// ---------------- kernel A: flash ctx + stats, LDS-staged K/V (r10) ----------
__global__ __launch_bounds__(512, 2) void attn_ctx_kernel(
    const unsigned short* __restrict__ Qh,
    const unsigned short* __restrict__ Kh,
    const unsigned short* __restrict__ Vt,
    float* __restrict__ stats,
    unsigned short* __restrict__ ctx)
{
    __shared__ unsigned short ldsK[2][64 * 64];   // 16 KB
    __shared__ unsigned short ldsV[2][64 * 64];   // 16 KB
    __shared__ unsigned short pS[8][16 * 72];     // 18 KB

    const int tid  = threadIdx.x;
    const int lane = tid & 63;
    const int w    = tid >> 6;          // 0..7
    const int g    = lane >> 4, r16 = lane & 15;
    const int wg   = w & 3;             // row-group within qtile
    const int grp  = w >> 2;            // 0 = heavy, 1 = light

    const int lid = blockIdx.x;         // 0..255 ; lid%8 = XCD
    const int xcd = lid & 7;
    const int rest = lid >> 3;          // 0..31
    const int bh  = xcd * 4 + (rest >> 3);
    const int ii  = rest & 7;           // 0..7
    const int b   = bh >> 4, h = bh & 15;

    const unsigned short* Kp = Kh + (size_t)bh * S_LEN * DHEAD;
    const unsigned short* Vp = Vt + (size_t)bh * DHEAD * S_LEN;

    const int srow = tid >> 3;              // staging row (0..63)
    const int scol = (tid & 7) * 16;        // staging byte col
    const int sswz = scol ^ ((srow & 7) << 4);
    const int rsw  = (r16 & 7) << 4;        // read-side XOR

    unsigned short* pl = pS[w];

    for (int pp = 0; pp < 2; ++pp) {
        const int p  = pp == 0 ? ii : 15 - ii;
        const int qh = 16 + p;              // heavy qtile
        const int ql = 15 - p;              // light qtile
        const int qtile = grp == 0 ? qh : ql;
        const int qw    = qtile * 64 + wg * 16;
        const int qrel  = wg * 16 + r16;
        const int myN   = qtile;            // compute while t <= myN

        const unsigned short* Qp = Qh + ((size_t)bh * S_LEN + qw) * DHEAD;
        bf16x8 qf[2];
#pragma unroll
        for (int d2 = 0; d2 < 2; ++d2)
            qf[d2] = *reinterpret_cast<const bf16x8*>(Qp + (size_t)r16 * DHEAD + d2 * 32 + g * 8);

        auto stageKV = [&](int kt, int buf) {
            gload_lds16((const char*)Kp + (size_t)(kt * 64 + srow) * 128 + sswz,
                        (char*)ldsK[buf] + tid * 16);
            gload_lds16((const char*)Vp + (size_t)srow * (S_LEN * 2) + (size_t)kt * 128 + sswz,
                        (char*)ldsV[buf] + tid * 16);
        };

        float l_run = 0.f;
        f32x4 of[4];
#pragma unroll
        for (int nt = 0; nt < 4; ++nt) of[nt] = (f32x4){0, 0, 0, 0};

        int buf = 0;
        stageKV(0, 0);
        __syncthreads();
        for (int t = 0; t <= qh; ++t) {
            if (t < qh) stageKV(t + 1, buf ^ 1);
            if (t <= myN) {
                const bool masked = (t == myN);
                bf16x8 kf[8];
#pragma unroll
                for (int d2 = 0; d2 < 2; ++d2)
#pragma unroll
                    for (int nt = 0; nt < 4; ++nt)
                        kf[d2 * 4 + nt] = *reinterpret_cast<const bf16x8*>(
                            (const char*)ldsK[buf] + (nt * 16 + r16) * 128 + ((d2 * 64 + g * 16) ^ rsw));
                f32x4 sf[4];
#pragma unroll
                for (int nt = 0; nt < 4; ++nt) sf[nt] = (f32x4){0, 0, 0, 0};
                __builtin_amdgcn_s_setprio(1);
#pragma unroll
                for (int d2 = 0; d2 < 2; ++d2)
#pragma unroll
                    for (int nt = 0; nt < 4; ++nt)
                        sf[nt] = __builtin_amdgcn_mfma_f32_16x16x32_bf16(kf[d2 * 4 + nt], qf[d2], sf[nt], 0, 0, 0);
                __builtin_amdgcn_s_setprio(0);
                float sum = 0.f;
#pragma unroll
                for (int nt = 0; nt < 4; ++nt)
#pragma unroll
                    for (int rr = 0; rr < 4; ++rr) {
                        float e = __builtin_amdgcn_exp2f(sf[nt][rr]);   // unnormalized
                        if (masked && (nt * 16 + g * 4 + rr > qrel)) e = 0.f;
                        sf[nt][rr] = e;
                        sum += e;
                    }
                l_run += sum;
#pragma unroll
                for (int nt = 0; nt < 4; ++nt) {
                    uint2 pk2;
                    pk2.x = cvt_pk_bf16(sf[nt][0], sf[nt][1]);
                    pk2.y = cvt_pk_bf16(sf[nt][2], sf[nt][3]);
                    *reinterpret_cast<uint2*>(&pl[r16 * 72 + nt * 16 + g * 4]) = pk2;
                }
                __builtin_amdgcn_wave_barrier();
                __builtin_amdgcn_s_setprio(1);
#pragma unroll
                for (int kh = 0; kh < 2; ++kh) {
                    bf16x8 pa = *reinterpret_cast<const bf16x8*>(&pl[r16 * 72 + kh * 32 + g * 8]);
#pragma unroll
                    for (int nt = 0; nt < 4; ++nt) {
                        bf16x8 vf = *reinterpret_cast<const bf16x8*>(
                            (const char*)ldsV[buf] + (nt * 16 + r16) * 128 + ((kh * 64 + g * 16) ^ rsw));
                        of[nt] = __builtin_amdgcn_mfma_f32_16x16x32_bf16(vf, pa, of[nt], 0, 0, 0);
                    }
                }
                __builtin_amdgcn_s_setprio(0);
            }
            __syncthreads();   // publishes buf^1, guards buf overwrite
            buf ^= 1;
        }

        float lx = l_run;
        lx += __shfl_xor(lx, 16);
        lx += __shfl_xor(lx, 32);
        const float mprime = __builtin_amdgcn_logf(lx);   // log2(l)
        if (lane < 16)
            stats[(size_t)bh * S_LEN + qw + r16] = mprime;

        const float inv = 1.f / lx;
        const size_t crow = ((size_t)b * S_LEN + qw + r16) * D_MODEL + h * DHEAD;
#pragma unroll
        for (int nt = 0; nt < 4; ++nt) {
            uint2 pk2;
            pk2.x = cvt_pk_bf16(of[nt][0] * inv, of[nt][1] * inv);
            pk2.y = cvt_pk_bf16(of[nt][2] * inv, of[nt][3] * inv);
            *reinterpret_cast<uint2*>(&ctx[crow + nt * 16 + g * 4]) = pk2;
        }
        __syncthreads();   // pass boundary: LDS reuse safe
    }
}

// ---------------- fused output: gemm_o (256) + 64x128 P-chunk writer (8704) ---
// r13 structure (best measured): mirror zeros inside P blocks, nt stores.
__global__ __launch_bounds__(256) void fused_out(
    const unsigned short* __restrict__ ctx,
    const float* __restrict__ wo_w,
    const float* __restrict__ wo_b,
    float* __restrict__ yout,
    const unsigned short* __restrict__ Qh,
    const unsigned short* __restrict__ Kh,
    const float* __restrict__ stats,
    float* __restrict__ attn_out)
{
    __shared__ unsigned short lds[64 * 136 + 64];   // 17.5 KB (gemm uses 16 KB)
    const int bid = blockIdx.x;
    if (bid < 256) {
        gemm_body<2, 0, 1>(lds, lds + 128 * 32, ctx, wo_w, wo_b, yout, bid & 7, bid >> 3, 1.0f);
        return;
    }

    const int tid  = threadIdx.x;
    const int lane = tid & 63;
    const int w    = tid >> 6;          // 0..3
    const int g    = lane >> 4, r16 = lane & 15;
    const int rl   = lane >> 4;
    const int c4   = (lane & 15) * 4;

    // decode: pid%8 = XCD, each XCD owns 4 bh x 272 chunks.
    const int pid = bid - 256;          // 0..8703
    const int xcd = pid & 7;
    const int cid = pid >> 3;           // 0..1087
    const int bh  = xcd * 4 + cid / 272;
    const int t   = cid % 272;
    int m = (int)((sqrtf(4.f * t + 1.f) - 1.f) * 0.5f);
    while (m * (m + 1) > t) --m;
    while ((m + 1) * (m + 2) <= t) ++m;
    int qt, c2;
    if (t < (m + 1) * (m + 1)) { qt = 2 * m;     c2 = t - m * (m + 1); }
    else                       { qt = 2 * m + 1; c2 = t - (m + 1) * (m + 1); }

    float* abase = attn_out + (size_t)bh * S_LEN * S_LEN;

    // 1) mirror zeros (tiles (2c2,qt),(2c2+1,qt) when strictly upper)
    const f32x4 z4 = (f32x4){0.f, 0.f, 0.f, 0.f};
#pragma unroll
    for (int s = 0; s < 2; ++s) {
        const int tr = 2 * c2 + s;
        if (qt > tr) {
            float* dstZ = abase + (size_t)(tr * 64) * S_LEN + qt * 64;
#pragma unroll
            for (int i = 0; i < 4; ++i) {
                const int r = w * 16 + i * 4 + rl;
                __builtin_nontemporal_store(z4,
                    reinterpret_cast<f32x4*>(dstZ + (size_t)r * S_LEN + c4));
            }
        }
    }

    // 2) P chunk (qt, cols c2*128 .. c2*128+127)
    const int qw   = qt * 64 + w * 16;
    const int qrel = w * 16 + r16;
    const unsigned short* Qp = Qh + ((size_t)bh * S_LEN + qw) * DHEAD;
    const unsigned short* Kp = Kh + (size_t)bh * S_LEN * DHEAD;

    bf16x8 qf[2];
#pragma unroll
    for (int d2 = 0; d2 < 2; ++d2)
        qf[d2] = *reinterpret_cast<const bf16x8*>(Qp + (size_t)r16 * DHEAD + d2 * 32 + g * 8);
    const float mpr = stats[(size_t)bh * S_LEN + qw + r16];

    unsigned short* plw = lds + w * (16 * 136);

#pragma unroll
    for (int kl = 0; kl < 2; ++kl) {
        const int kt = 2 * c2 + kl;
        if (kt > qt) {
            const uint2 zz = {0u, 0u};
#pragma unroll
            for (int nt = 0; nt < 4; ++nt)
                *reinterpret_cast<uint2*>(&plw[r16 * 136 + kl * 64 + nt * 16 + g * 4]) = zz;
            continue;
        }
        bf16x8 kf[8];
#pragma unroll
        for (int d2 = 0; d2 < 2; ++d2)
#pragma unroll
            for (int nt = 0; nt < 4; ++nt)
                kf[d2 * 4 + nt] = *reinterpret_cast<const bf16x8*>(
                    Kp + (size_t)(kt * 64 + nt * 16 + r16) * DHEAD + d2 * 32 + g * 8);
        f32x4 sf[4];
#pragma unroll
        for (int nt = 0; nt < 4; ++nt) sf[nt] = (f32x4){0, 0, 0, 0};
        __builtin_amdgcn_s_setprio(1);
#pragma unroll
        for (int d2 = 0; d2 < 2; ++d2)
#pragma unroll
            for (int nt = 0; nt < 4; ++nt)
                sf[nt] = __builtin_amdgcn_mfma_f32_16x16x32_bf16(kf[d2 * 4 + nt], qf[d2], sf[nt], 0, 0, 0);
        __builtin_amdgcn_s_setprio(0);
        const bool masked = (kt == qt);
#pragma unroll
        for (int nt = 0; nt < 4; ++nt) {
#pragma unroll
            for (int rr = 0; rr < 4; ++rr) {
                float p = __builtin_amdgcn_exp2f(sf[nt][rr] - mpr);
                if (masked && (nt * 16 + g * 4 + rr > qrel)) p = 0.f;
                sf[nt][rr] = p;
            }
            uint2 pk2;
            pk2.x = cvt_pk_bf16(sf[nt][0], sf[nt][1]);
            pk2.y = cvt_pk_bf16(sf[nt][2], sf[nt][3]);
            *reinterpret_cast<uint2*>(&plw[r16 * 136 + kl * 64 + nt * 16 + g * 4]) = pk2;
        }
    }
    __builtin_amdgcn_wave_barrier();

    // readback: 8 insts x (2 rows x 512B) = 1 KB contiguous pairs, nt stores
    float* dst0 = abase + (size_t)qw * S_LEN + c2 * 128;
    const int rsub = lane >> 5;             // 0..1
    const int cc2  = (lane & 31) * 4;       // 0..124
#pragma unroll
    for (int i = 0; i < 8; ++i) {
        const int r = i * 2 + rsub;
        uint2 d = *reinterpret_cast<const uint2*>(&plw[r * 136 + cc2]);
        f32x4 o;
        o[0] = bf2f(d.x & 0xffffu);
        o[1] = bf2f(d.x >> 16);
        o[2] = bf2f(d.y & 0xffffu);
        o[3] = bf2f(d.y >> 16);
        __builtin_nontemporal_store(o, reinterpret_cast<f32x4*>(dst0 + (size_t)r * S_LEN + cc2));
    }
}

extern "C" void kernel_launch(void* const* d_in, const int* in_sizes, int n_in,
                              void* d_out, int out_size, void* d_ws, size_t ws_size,
                              hipStream_t stream)
{
    const float* q    = (const float*)d_in[0];
    const float* k    = (const float*)d_in[1];
    const float* v    = (const float*)d_in[2];
    const float* wq_w = (const float*)d_in[4];
    const float* wq_b = (const float*)d_in[5];
    const float* wk_w = (const float*)d_in[6];
    const float* wk_b = (const float*)d_in[7];
    const float* wv_w = (const float*)d_in[8];
    const float* wv_b = (const float*)d_in[9];
    const float* wo_w = (const float*)d_in[10];
    const float* wo_b = (const float*)d_in[11];

    char* ws = (char*)d_ws;
    const size_t MB = 1024 * 1024;
    unsigned short* Qhp = (unsigned short*)(ws + 32 * MB);
    unsigned short* Khp = (unsigned short*)(ws + 40 * MB);
    unsigned short* Vtp = (unsigned short*)(ws + 48 * MB);
    unsigned short* ctx = (unsigned short*)(ws + 56 * MB);
    float* stats = (float*)(ws + 0 * MB);

    float* yout = (float*)d_out;
    float* attn = yout + (size_t)M_ROWS * D_MODEL;

    const float qscale = 0.125f * 1.44269504088896340736f;  // fold scale*log2(e) into Q
    proj_all<<<dim3(768), dim3(256), 0, stream>>>(
        q, wq_w, wq_b, Qhp,
        k, wk_w, wk_b, Khp,
        v, wv_w, wv_b, Vtp, qscale);

    attn_ctx_kernel<<<dim3(256), dim3(512), 0, stream>>>(Qhp, Khp, Vtp, stats, ctx);

    fused_out<<<dim3(256 + 8704), dim3(256), 0, stream>>>(
        ctx, wo_w, wo_b, yout, Qhp, Khp, stats, attn);
}

// Round 17
// 217.683 us; speedup vs baseline: 1.1675x; 1.0672x over previous
//
#include <hip/hip_runtime.h>
#include <cstdint>

#define S_LEN   2048
#define D_MODEL 1024
#define NHEAD   16
#define DHEAD   64
#define BATCH   2
#define M_ROWS  (BATCH * S_LEN)   // 4096

typedef __attribute__((ext_vector_type(8))) short bf16x8;
typedef __attribute__((ext_vector_type(4))) float f32x4;

__device__ __forceinline__ unsigned short f2bf(float f) {
    union { float f; uint32_t u; } v; v.f = f;
    uint32_t u = v.u;
    return (unsigned short)((u + 0x7FFFu + ((u >> 16) & 1u)) >> 16);
}

__device__ __forceinline__ float bf2f(uint32_t u16) {
    union { uint32_t u; float f; } x; x.u = u16 << 16; return x.f;
}

__device__ __forceinline__ uint32_t cvt_pk_bf16(float a, float b) {
    uint32_t r;
    asm("v_cvt_pk_bf16_f32 %0, %1, %2" : "=v"(r) : "v"(a), "v"(b));
    return r;
}

__device__ __forceinline__ void gload_lds16(const void* g, void* l) {
    __builtin_amdgcn_global_load_lds(
        (const __attribute__((address_space(1))) void*)g,
        (__attribute__((address_space(3))) void*)l, 16, 0, 0);
}

// ---------------- fused f32 -> bf16 convert ----------------
struct CvtArgs {
    const float* src[7];
    unsigned short* dst[7];
    int n4[7];
};
__global__ __launch_bounds__(256) void cvt_all(CvtArgs a) {
    const int which = blockIdx.y;
    const int t = blockIdx.x * 256 + threadIdx.x;
    if (t >= a.n4[which]) return;
    f32x4 v = reinterpret_cast<const f32x4*>(a.src[which])[t];
    uint2 o;
    o.x = cvt_pk_bf16(v[0], v[1]);
    o.y = cvt_pk_bf16(v[2], v[3]);
    reinterpret_cast<uint2*>(a.dst[which])[t] = o;
}

// ---------------- GEMM body: C = A @ Bw^T + bias (K=1024) ----------------
template<int MODE>
__device__ __forceinline__ void gemm_body(
    unsigned short* lA, unsigned short* lB,
    const unsigned short* __restrict__ A,
    const unsigned short* __restrict__ Bw,
    const float* __restrict__ bias,
    void* __restrict__ Cout,
    int bx, int by, float prescale)
{
    constexpr int K = 1024;
    const int tid  = threadIdx.x;
    const int lane = tid & 63;
    const int w    = tid >> 6;
    const int wr   = w >> 1, wc = w & 1;
    const int g    = lane >> 4, r16 = lane & 15;
    const int brow = by * 128;
    const int bcol = bx * 128;

    f32x4 acc[4][4];
#pragma unroll
    for (int i = 0; i < 4; ++i)
#pragma unroll
        for (int j = 0; j < 4; ++j) acc[i][j] = (f32x4){0.f, 0.f, 0.f, 0.f};

    const int rA0 = tid >> 2;
    const int cc  = (tid & 3) * 8;

    for (int kk = 0; kk < K; kk += 32) {
#pragma unroll
        for (int it = 0; it < 2; ++it) {
            int r = it * 64 + rA0;
            gload_lds16(A  + (size_t)(brow + r) * K + kk + cc, &lA[r * 32 + cc]);
            gload_lds16(Bw + (size_t)(bcol + r) * K + kk + cc, &lB[r * 32 + cc]);
        }
        __syncthreads();
        bf16x8 af[4], bfr[4];
#pragma unroll
        for (int i = 0; i < 4; ++i)
            af[i] = *reinterpret_cast<const bf16x8*>(&lA[(wr * 64 + i * 16 + r16) * 32 + g * 8]);
#pragma unroll
        for (int j = 0; j < 4; ++j)
            bfr[j] = *reinterpret_cast<const bf16x8*>(&lB[(wc * 64 + j * 16 + r16) * 32 + g * 8]);
#pragma unroll
        for (int i = 0; i < 4; ++i)
#pragma unroll
            for (int j = 0; j < 4; ++j)
                acc[i][j] = __builtin_amdgcn_mfma_f32_16x16x32_bf16(af[i], bfr[j], acc[i][j], 0, 0, 0);
        __syncthreads();
    }

#pragma unroll
    for (int i = 0; i < 4; ++i) {
#pragma unroll
        for (int j = 0; j < 4; ++j) {
            const int n = bcol + wc * 64 + j * 16 + r16;
#pragma unroll
            for (int rr = 0; rr < 4; ++rr) {
                const int m = brow + wr * 64 + i * 16 + g * 4 + rr;
                float val = acc[i][j][rr];
                if (MODE == 0) {
                    val = (val + bias[n]) * prescale;
                    int b = m >> 11, s = m & 2047;
                    int h = n >> 6,  d = n & 63;
                    ((unsigned short*)Cout)[(((size_t)(b * NHEAD + h)) * S_LEN + s) * DHEAD + d] = f2bf(val);
                } else if (MODE == 1) {
                    val += bias[m];
                    int h = m >> 6,  d = m & 63;
                    int b = n >> 11, s = n & 2047;
                    ((unsigned short*)Cout)[(((size_t)(b * NHEAD + h)) * DHEAD + d) * S_LEN + s] = f2bf(val);
                } else {
                    val += bias[n];
                    ((float*)Cout)[(size_t)m * D_MODEL + n] = val;
                }
            }
        }
    }
}

// ---------------- merged Q/K/V projections (768 blocks) ----------------
__global__ __launch_bounds__(256) void proj_all(
    const unsigned short* qb, const unsigned short* wqb, const float* wq_b, unsigned short* Qhp,
    const unsigned short* kb, const unsigned short* wkb, const float* wk_b, unsigned short* Khp,
    const unsigned short* vb, const unsigned short* wvb, const float* wv_b, unsigned short* Vtp,
    float qscale)
{
    __shared__ unsigned short lA[128 * 32];
    __shared__ unsigned short lB[128 * 32];
    const int bid = blockIdx.x;
    const int z = bid >> 8, t = bid & 255;
    if (z == 0)
        gemm_body<0>(lA, lB, qb, wqb, wq_b, Qhp, t & 7, t >> 3, qscale);
    else if (z == 1)
        gemm_body<0>(lA, lB, kb, wkb, wk_b, Khp, t & 7, t >> 3, 1.0f);
    else
        gemm_body<1>(lA, lB, wvb, vb, wv_b, Vtp, t & 31, t >> 5, 1.0f);
}

// ---------------- kernel A: flash ctx + stats, LDS-staged K/V ----------------
// 512 blocks (2/CU), one qtile-pair per block. Blocks j and j+256 carry
// complementary pair sizes (17+p and 32-p iters, sum 49) so each CU's two
// co-resident blocks have equal total work; their independent barrier/staging
// stalls overlap (latency hiding that the serial 1-block/CU version lacked).
__global__ __launch_bounds__(512, 2) void attn_ctx_kernel(
    const unsigned short* __restrict__ Qh,
    const unsigned short* __restrict__ Kh,
    const unsigned short* __restrict__ Vt,
    float* __restrict__ stats,
    unsigned short* __restrict__ ctx)
{
    __shared__ unsigned short ldsK[2][64 * 64];   // 16 KB
    __shared__ unsigned short ldsV[2][64 * 64];   // 16 KB
    __shared__ unsigned short pS[8][16 * 72];     // 18 KB

    const int tid  = threadIdx.x;
    const int lane = tid & 63;
    const int w    = tid >> 6;          // 0..7
    const int g    = lane >> 4, r16 = lane & 15;
    const int wg   = w & 3;             // row-group within qtile
    const int grp  = w >> 2;            // 0 = heavy, 1 = light

    const int half = blockIdx.x >> 8;   // 0 or 1 (complementary halves)
    const int base = blockIdx.x & 255;  // 0..255 ; base%8 = XCD
    const int xcd = base & 7;
    const int rest = base >> 3;         // 0..31
    const int bh  = xcd * 4 + (rest >> 3);
    const int ii  = rest & 7;           // 0..7
    const int p   = (half == 0) ? ii : 15 - ii;
    const int b   = bh >> 4, h = bh & 15;

    const unsigned short* Kp = Kh + (size_t)bh * S_LEN * DHEAD;
    const unsigned short* Vp = Vt + (size_t)bh * DHEAD * S_LEN;

    const int srow = tid >> 3;              // staging row (0..63)
    const int scol = (tid & 7) * 16;        // staging byte col
    const int sswz = scol ^ ((srow & 7) << 4);
    const int rsw  = (r16 & 7) << 4;        // read-side XOR

    unsigned short* pl = pS[w];

    const int qh = 16 + p;              // heavy qtile
    const int ql = 15 - p;              // light qtile
    const int qtile = grp == 0 ? qh : ql;
    const int qw    = qtile * 64 + wg * 16;
    const int qrel  = wg * 16 + r16;
    const int myN   = qtile;            // compute while t <= myN

    const unsigned short* Qp = Qh + ((size_t)bh * S_LEN + qw) * DHEAD;
    bf16x8 qf[2];
#pragma unroll
    for (int d2 = 0; d2 < 2; ++d2)
        qf[d2] = *reinterpret_cast<const bf16x8*>(Qp + (size_t)r16 * DHEAD + d2 * 32 + g * 8);

    auto stageKV = [&](int kt, int buf) {
        gload_lds16((const char*)Kp + (size_t)(kt * 64 + srow) * 128 + sswz,
                    (char*)ldsK[buf] + tid * 16);
        gload_lds16((const char*)Vp + (size_t)srow * (S_LEN * 2) + (size_t)kt * 128 + sswz,
                    (char*)ldsV[buf] + tid * 16);
    };

    float l_run = 0.f;
    f32x4 of[4];
#pragma unroll
    for (int nt = 0; nt < 4; ++nt) of[nt] = (f32x4){0, 0, 0, 0};

    int buf = 0;
    stageKV(0, 0);
    __syncthreads();
    for (int t = 0; t <= qh; ++t) {
        if (t < qh) stageKV(t + 1, buf ^ 1);
        if (t <= myN) {
            const bool masked = (t == myN);
            bf16x8 kf[8];
#pragma unroll
            for (int d2 = 0; d2 < 2; ++d2)
#pragma unroll
                for (int nt = 0; nt < 4; ++nt)
                    kf[d2 * 4 + nt] = *reinterpret_cast<const bf16x8*>(
                        (const char*)ldsK[buf] + (nt * 16 + r16) * 128 + ((d2 * 64 + g * 16) ^ rsw));
            f32x4 sf[4];
#pragma unroll
            for (int nt = 0; nt < 4; ++nt) sf[nt] = (f32x4){0, 0, 0, 0};
            __builtin_amdgcn_s_setprio(1);
#pragma unroll
            for (int d2 = 0; d2 < 2; ++d2)
#pragma unroll
                for (int nt = 0; nt < 4; ++nt)
                    sf[nt] = __builtin_amdgcn_mfma_f32_16x16x32_bf16(kf[d2 * 4 + nt], qf[d2], sf[nt], 0, 0, 0);
            __builtin_amdgcn_s_setprio(0);
            float sum = 0.f;
#pragma unroll
            for (int nt = 0; nt < 4; ++nt)
#pragma unroll
                for (int rr = 0; rr < 4; ++rr) {
                    float e = __builtin_amdgcn_exp2f(sf[nt][rr]);   // unnormalized
                    if (masked && (nt * 16 + g * 4 + rr > qrel)) e = 0.f;
                    sf[nt][rr] = e;
                    sum += e;
                }
            l_run += sum;
#pragma unroll
            for (int nt = 0; nt < 4; ++nt) {
                uint2 pk2;
                pk2.x = cvt_pk_bf16(sf[nt][0], sf[nt][1]);
                pk2.y = cvt_pk_bf16(sf[nt][2], sf[nt][3]);
                *reinterpret_cast<uint2*>(&pl[r16 * 72 + nt * 16 + g * 4]) = pk2;
            }
            __builtin_amdgcn_wave_barrier();
            __builtin_amdgcn_s_setprio(1);
#pragma unroll
            for (int kh = 0; kh < 2; ++kh) {
                bf16x8 pa = *reinterpret_cast<const bf16x8*>(&pl[r16 * 72 + kh * 32 + g * 8]);
#pragma unroll
                for (int nt = 0; nt < 4; ++nt) {
                    bf16x8 vf = *reinterpret_cast<const bf16x8*>(
                        (const char*)ldsV[buf] + (nt * 16 + r16) * 128 + ((kh * 64 + g * 16) ^ rsw));
                    of[nt] = __builtin_amdgcn_mfma_f32_16x16x32_bf16(vf, pa, of[nt], 0, 0, 0);
                }
            }
            __builtin_amdgcn_s_setprio(0);
        }
        __syncthreads();   // publishes buf^1, guards buf overwrite
        buf ^= 1;
    }

    float lx = l_run;
    lx += __shfl_xor(lx, 16);
    lx += __shfl_xor(lx, 32);
    const float mprime = __builtin_amdgcn_logf(lx);   // log2(l)
    if (lane < 16)
        stats[(size_t)bh * S_LEN + qw + r16] = mprime;

    const float inv = 1.f / lx;
    const size_t crow = ((size_t)b * S_LEN + qw + r16) * D_MODEL + h * DHEAD;
#pragma unroll
    for (int nt = 0; nt < 4; ++nt) {
        uint2 pk2;
        pk2.x = cvt_pk_bf16(of[nt][0] * inv, of[nt][1] * inv);
        pk2.y = cvt_pk_bf16(of[nt][2] * inv, of[nt][3] * inv);
        *reinterpret_cast<uint2*>(&ctx[crow + nt * 16 + g * 4]) = pk2;
    }
}

// ---------------- fused output: gemm_o (256) + 64x128 P-chunk writer (8704) ---
// r13 structure (best measured): mirror zeros inside P blocks, nt stores.
__global__ __launch_bounds__(256) void fused_out(
    const unsigned short* __restrict__ ctx,
    const unsigned short* __restrict__ wob,
    const float* __restrict__ wo_b,
    float* __restrict__ yout,
    const unsigned short* __restrict__ Qh,
    const unsigned short* __restrict__ Kh,
    const float* __restrict__ stats,
    float* __restrict__ attn_out)
{
    __shared__ unsigned short lds[64 * 136 + 64];   // 17.5 KB (gemm uses 16 KB)
    const int bid = blockIdx.x;
    if (bid < 256) {
        gemm_body<2>(lds, lds + 128 * 32, ctx, wob, wo_b, yout, bid & 7, bid >> 3, 1.0f);
        return;
    }

    const int tid  = threadIdx.x;
    const int lane = tid & 63;
    const int w    = tid >> 6;          // 0..3
    const int g    = lane >> 4, r16 = lane & 15;
    const int rl   = lane >> 4;
    const int c4   = (lane & 15) * 4;

    // decode: pid%8 = XCD, each XCD owns 4 bh x 272 chunks.
    const int pid = bid - 256;          // 0..8703
    const int xcd = pid & 7;
    const int cid = pid >> 3;           // 0..1087
    const int bh  = xcd * 4 + cid / 272;
    const int t   = cid % 272;
    int m = (int)((sqrtf(4.f * t + 1.f) - 1.f) * 0.5f);
    while (m * (m + 1) > t) --m;
    while ((m + 1) * (m + 2) <= t) ++m;
    int qt, c2;
    if (t < (m + 1) * (m + 1)) { qt = 2 * m;     c2 = t - m * (m + 1); }
    else                       { qt = 2 * m + 1; c2 = t - (m + 1) * (m + 1); }

    float* abase = attn_out + (size_t)bh * S_LEN * S_LEN;

    // 1) mirror zeros (tiles (2c2,qt),(2c2+1,qt) when strictly upper)
    const f32x4 z4 = (f32x4){0.f, 0.f, 0.f, 0.f};
#pragma unroll
    for (int s = 0; s < 2; ++s) {
        const int tr = 2 * c2 + s;
        if (qt > tr) {
            float* dstZ = abase + (size_t)(tr * 64) * S_LEN + qt * 64;
#pragma unroll
            for (int i = 0; i < 4; ++i) {
                const int r = w * 16 + i * 4 + rl;
                __builtin_nontemporal_store(z4,
                    reinterpret_cast<f32x4*>(dstZ + (size_t)r * S_LEN + c4));
            }
        }
    }

    // 2) P chunk (qt, cols c2*128 .. c2*128+127)
    const int qw   = qt * 64 + w * 16;
    const int qrel = w * 16 + r16;
    const unsigned short* Qp = Qh + ((size_t)bh * S_LEN + qw) * DHEAD;
    const unsigned short* Kp = Kh + (size_t)bh * S_LEN * DHEAD;

    bf16x8 qf[2];
#pragma unroll
    for (int d2 = 0; d2 < 2; ++d2)
        qf[d2] = *reinterpret_cast<const bf16x8*>(Qp + (size_t)r16 * DHEAD + d2 * 32 + g * 8);
    const float mpr = stats[(size_t)bh * S_LEN + qw + r16];

    unsigned short* plw = lds + w * (16 * 136);

#pragma unroll
    for (int kl = 0; kl < 2; ++kl) {
        const int kt = 2 * c2 + kl;
        if (kt > qt) {
            const uint2 zz = {0u, 0u};
#pragma unroll
            for (int nt = 0; nt < 4; ++nt)
                *reinterpret_cast<uint2*>(&plw[r16 * 136 + kl * 64 + nt * 16 + g * 4]) = zz;
            continue;
        }
        bf16x8 kf[8];
#pragma unroll
        for (int d2 = 0; d2 < 2; ++d2)
#pragma unroll
            for (int nt = 0; nt < 4; ++nt)
                kf[d2 * 4 + nt] = *reinterpret_cast<const bf16x8*>(
                    Kp + (size_t)(kt * 64 + nt * 16 + r16) * DHEAD + d2 * 32 + g * 8);
        f32x4 sf[4];
#pragma unroll
        for (int nt = 0; nt < 4; ++nt) sf[nt] = (f32x4){0, 0, 0, 0};
        __builtin_amdgcn_s_setprio(1);
#pragma unroll
        for (int d2 = 0; d2 < 2; ++d2)
#pragma unroll
            for (int nt = 0; nt < 4; ++nt)
                sf[nt] = __builtin_amdgcn_mfma_f32_16x16x32_bf16(kf[d2 * 4 + nt], qf[d2], sf[nt], 0, 0, 0);
        __builtin_amdgcn_s_setprio(0);
        const bool masked = (kt == qt);
#pragma unroll
        for (int nt = 0; nt < 4; ++nt) {
#pragma unroll
            for (int rr = 0; rr < 4; ++rr) {
                float p = __builtin_amdgcn_exp2f(sf[nt][rr] - mpr);
                if (masked && (nt * 16 + g * 4 + rr > qrel)) p = 0.f;
                sf[nt][rr] = p;
            }
            uint2 pk2;
            pk2.x = cvt_pk_bf16(sf[nt][0], sf[nt][1]);
            pk2.y = cvt_pk_bf16(sf[nt][2], sf[nt][3]);
            *reinterpret_cast<uint2*>(&plw[r16 * 136 + kl * 64 + nt * 16 + g * 4]) = pk2;
        }
    }
    __builtin_amdgcn_wave_barrier();

    // readback: 8 insts x (2 rows x 512B) = 1 KB contiguous pairs, nt stores
    float* dst0 = abase + (size_t)qw * S_LEN + c2 * 128;
    const int rsub = lane >> 5;             // 0..1
    const int cc2  = (lane & 31) * 4;       // 0..124
#pragma unroll
    for (int i = 0; i < 8; ++i) {
        const int r = i * 2 + rsub;
        uint2 d = *reinterpret_cast<const uint2*>(&plw[r * 136 + cc2]);
        f32x4 o;
        o[0] = bf2f(d.x & 0xffffu);
        o[1] = bf2f(d.x >> 16);
        o[2] = bf2f(d.y & 0xffffu);
        o[3] = bf2f(d.y >> 16);
        __builtin_nontemporal_store(o, reinterpret_cast<f32x4*>(dst0 + (size_t)r * S_LEN + cc2));
    }
}

extern "C" void kernel_launch(void* const* d_in, const int* in_sizes, int n_in,
                              void* d_out, int out_size, void* d_ws, size_t ws_size,
                              hipStream_t stream)
{
    const float* q    = (const float*)d_in[0];
    const float* k    = (const float*)d_in[1];
    const float* v    = (const float*)d_in[2];
    const float* wq_w = (const float*)d_in[4];
    const float* wq_b = (const float*)d_in[5];
    const float* wk_w = (const float*)d_in[6];
    const float* wk_b = (const float*)d_in[7];
    const float* wv_w = (const float*)d_in[8];
    const float* wv_b = (const float*)d_in[9];
    const float* wo_w = (const float*)d_in[10];
    const float* wo_b = (const float*)d_in[11];

    char* ws = (char*)d_ws;
    const size_t MB = 1024 * 1024;
    unsigned short* qb  = (unsigned short*)(ws + 0 * MB);
    unsigned short* kb  = (unsigned short*)(ws + 8 * MB);
    unsigned short* vb  = (unsigned short*)(ws + 16 * MB);
    unsigned short* wqb = (unsigned short*)(ws + 24 * MB);
    unsigned short* wkb = (unsigned short*)(ws + 26 * MB);
    unsigned short* wvb = (unsigned short*)(ws + 28 * MB);
    unsigned short* wob = (unsigned short*)(ws + 30 * MB);
    unsigned short* Qhp = (unsigned short*)(ws + 32 * MB);
    unsigned short* Khp = (unsigned short*)(ws + 40 * MB);
    unsigned short* Vtp = (unsigned short*)(ws + 48 * MB);
    unsigned short* ctx = (unsigned short*)(ws + 56 * MB);
    // stats overlays qb (dead after projections; rewritten every launch)
    float* stats = (float*)(ws + 0 * MB);

    float* yout = (float*)d_out;
    float* attn = yout + (size_t)M_ROWS * D_MODEL;

    CvtArgs ca;
    ca.src[0] = q;    ca.dst[0] = qb;  ca.n4[0] = M_ROWS * D_MODEL / 4;
    ca.src[1] = k;    ca.dst[1] = kb;  ca.n4[1] = M_ROWS * D_MODEL / 4;
    ca.src[2] = v;    ca.dst[2] = vb;  ca.n4[2] = M_ROWS * D_MODEL / 4;
    ca.src[3] = wq_w; ca.dst[3] = wqb; ca.n4[3] = D_MODEL * D_MODEL / 4;
    ca.src[4] = wk_w; ca.dst[4] = wkb; ca.n4[4] = D_MODEL * D_MODEL / 4;
    ca.src[5] = wv_w; ca.dst[5] = wvb; ca.n4[5] = D_MODEL * D_MODEL / 4;
    ca.src[6] = wo_w; ca.dst[6] = wob; ca.n4[6] = D_MODEL * D_MODEL / 4;
    cvt_all<<<dim3((M_ROWS * D_MODEL / 4 + 255) / 256, 7), dim3(256), 0, stream>>>(ca);

    const float qscale = 0.125f * 1.44269504088896340736f;  // fold scale*log2(e) into Q
    proj_all<<<dim3(768), dim3(256), 0, stream>>>(
        qb, wqb, wq_b, Qhp,
        kb, wkb, wk_b, Khp,
        vb, wvb, wv_b, Vtp, qscale);

    attn_ctx_kernel<<<dim3(512), dim3(512), 0, stream>>>(Qhp, Khp, Vtp, stats, ctx);

    fused_out<<<dim3(256 + 8704), dim3(256), 0, stream>>>(
        ctx, wob, wo_b, yout, Qhp, Khp, stats, attn);
}

// Round 18
// 216.433 us; speedup vs baseline: 1.1743x; 1.0058x over previous
//
#include <hip/hip_runtime.h>
#include <cstdint>

#define S_LEN   2048
#define D_MODEL 1024
#define NHEAD   16
#define DHEAD   64
#define BATCH   2
#define M_ROWS  (BATCH * S_LEN)   // 4096

typedef __attribute__((ext_vector_type(8))) short bf16x8;
typedef __attribute__((ext_vector_type(4))) float f32x4;

__device__ __forceinline__ unsigned short f2bf(float f) {
    union { float f; uint32_t u; } v; v.f = f;
    uint32_t u = v.u;
    return (unsigned short)((u + 0x7FFFu + ((u >> 16) & 1u)) >> 16);
}

__device__ __forceinline__ float bf2f(uint32_t u16) {
    union { uint32_t u; float f; } x; x.u = u16 << 16; return x.f;
}

__device__ __forceinline__ uint32_t cvt_pk_bf16(float a, float b) {
    uint32_t r;
    asm("v_cvt_pk_bf16_f32 %0, %1, %2" : "=v"(r) : "v"(a), "v"(b));
    return r;
}

__device__ __forceinline__ void gload_lds16(const void* g, void* l) {
    __builtin_amdgcn_global_load_lds(
        (const __attribute__((address_space(1))) void*)g,
        (__attribute__((address_space(3))) void*)l, 16, 0, 0);
}

// ---------------- fused f32 -> bf16 convert ----------------
struct CvtArgs {
    const float* src[7];
    unsigned short* dst[7];
    int n4[7];
};
__global__ __launch_bounds__(256) void cvt_all(CvtArgs a) {
    const int which = blockIdx.y;
    const int t = blockIdx.x * 256 + threadIdx.x;
    if (t >= a.n4[which]) return;
    f32x4 v = reinterpret_cast<const f32x4*>(a.src[which])[t];
    uint2 o;
    o.x = cvt_pk_bf16(v[0], v[1]);
    o.y = cvt_pk_bf16(v[2], v[3]);
    reinterpret_cast<uint2*>(a.dst[which])[t] = o;
}

// ---------------- GEMM body: C = A @ Bw^T + bias (K=1024) ----------------
template<int MODE>
__device__ __forceinline__ void gemm_body(
    unsigned short* lA, unsigned short* lB,
    const unsigned short* __restrict__ A,
    const unsigned short* __restrict__ Bw,
    const float* __restrict__ bias,
    void* __restrict__ Cout,
    int bx, int by, float prescale)
{
    constexpr int K = 1024;
    const int tid  = threadIdx.x;
    const int lane = tid & 63;
    const int w    = tid >> 6;
    const int wr   = w >> 1, wc = w & 1;
    const int g    = lane >> 4, r16 = lane & 15;
    const int brow = by * 128;
    const int bcol = bx * 128;

    f32x4 acc[4][4];
#pragma unroll
    for (int i = 0; i < 4; ++i)
#pragma unroll
        for (int j = 0; j < 4; ++j) acc[i][j] = (f32x4){0.f, 0.f, 0.f, 0.f};

    const int rA0 = tid >> 2;
    const int cc  = (tid & 3) * 8;

    for (int kk = 0; kk < K; kk += 32) {
#pragma unroll
        for (int it = 0; it < 2; ++it) {
            int r = it * 64 + rA0;
            gload_lds16(A  + (size_t)(brow + r) * K + kk + cc, &lA[r * 32 + cc]);
            gload_lds16(Bw + (size_t)(bcol + r) * K + kk + cc, &lB[r * 32 + cc]);
        }
        __syncthreads();
        bf16x8 af[4], bfr[4];
#pragma unroll
        for (int i = 0; i < 4; ++i)
            af[i] = *reinterpret_cast<const bf16x8*>(&lA[(wr * 64 + i * 16 + r16) * 32 + g * 8]);
#pragma unroll
        for (int j = 0; j < 4; ++j)
            bfr[j] = *reinterpret_cast<const bf16x8*>(&lB[(wc * 64 + j * 16 + r16) * 32 + g * 8]);
#pragma unroll
        for (int i = 0; i < 4; ++i)
#pragma unroll
            for (int j = 0; j < 4; ++j)
                acc[i][j] = __builtin_amdgcn_mfma_f32_16x16x32_bf16(af[i], bfr[j], acc[i][j], 0, 0, 0);
        __syncthreads();
    }

#pragma unroll
    for (int i = 0; i < 4; ++i) {
#pragma unroll
        for (int j = 0; j < 4; ++j) {
            const int n = bcol + wc * 64 + j * 16 + r16;
#pragma unroll
            for (int rr = 0; rr < 4; ++rr) {
                const int m = brow + wr * 64 + i * 16 + g * 4 + rr;
                float val = acc[i][j][rr];
                if (MODE == 0) {
                    val = (val + bias[n]) * prescale;
                    int b = m >> 11, s = m & 2047;
                    int h = n >> 6,  d = n & 63;
                    ((unsigned short*)Cout)[(((size_t)(b * NHEAD + h)) * S_LEN + s) * DHEAD + d] = f2bf(val);
                } else if (MODE == 1) {
                    val += bias[m];
                    int h = m >> 6,  d = m & 63;
                    int b = n >> 11, s = n & 2047;
                    ((unsigned short*)Cout)[(((size_t)(b * NHEAD + h)) * DHEAD + d) * S_LEN + s] = f2bf(val);
                } else {
                    val += bias[n];
                    ((float*)Cout)[(size_t)m * D_MODEL + n] = val;
                }
            }
        }
    }
}

// ---------------- merged Q/K/V projections (768 blocks) ----------------
__global__ __launch_bounds__(256) void proj_all(
    const unsigned short* qb, const unsigned short* wqb, const float* wq_b, unsigned short* Qhp,
    const unsigned short* kb, const unsigned short* wkb, const float* wk_b, unsigned short* Khp,
    const unsigned short* vb, const unsigned short* wvb, const float* wv_b, unsigned short* Vtp,
    float qscale)
{
    __shared__ unsigned short lA[128 * 32];
    __shared__ unsigned short lB[128 * 32];
    const int bid = blockIdx.x;
    const int z = bid >> 8, t = bid & 255;
    if (z == 0)
        gemm_body<0>(lA, lB, qb, wqb, wq_b, Qhp, t & 7, t >> 3, qscale);
    else if (z == 1)
        gemm_body<0>(lA, lB, kb, wkb, wk_b, Khp, t & 7, t >> 3, 1.0f);
    else
        gemm_body<1>(lA, lB, wvb, vb, wv_b, Vtp, t & 31, t >> 5, 1.0f);
}

// ---------------- kernel A: flash ctx + stats (512 blocks, 2/CU) --------------
__global__ __launch_bounds__(512, 2) void attn_ctx_kernel(
    const unsigned short* __restrict__ Qh,
    const unsigned short* __restrict__ Kh,
    const unsigned short* __restrict__ Vt,
    float* __restrict__ stats,
    unsigned short* __restrict__ ctx)
{
    __shared__ unsigned short ldsK[2][64 * 64];   // 16 KB
    __shared__ unsigned short ldsV[2][64 * 64];   // 16 KB
    __shared__ unsigned short pS[8][16 * 72];     // 18 KB

    const int tid  = threadIdx.x;
    const int lane = tid & 63;
    const int w    = tid >> 6;          // 0..7
    const int g    = lane >> 4, r16 = lane & 15;
    const int wg   = w & 3;             // row-group within qtile
    const int grp  = w >> 2;            // 0 = heavy, 1 = light

    const int half = blockIdx.x >> 8;   // 0 or 1 (complementary halves)
    const int base = blockIdx.x & 255;  // 0..255 ; base%8 = XCD
    const int xcd = base & 7;
    const int rest = base >> 3;         // 0..31
    const int bh  = xcd * 4 + (rest >> 3);
    const int ii  = rest & 7;           // 0..7
    const int p   = (half == 0) ? ii : 15 - ii;
    const int b   = bh >> 4, h = bh & 15;

    const unsigned short* Kp = Kh + (size_t)bh * S_LEN * DHEAD;
    const unsigned short* Vp = Vt + (size_t)bh * DHEAD * S_LEN;

    const int srow = tid >> 3;              // staging row (0..63)
    const int scol = (tid & 7) * 16;        // staging byte col
    const int sswz = scol ^ ((srow & 7) << 4);
    const int rsw  = (r16 & 7) << 4;        // read-side XOR

    unsigned short* pl = pS[w];

    const int qh = 16 + p;              // heavy qtile
    const int ql = 15 - p;              // light qtile
    const int qtile = grp == 0 ? qh : ql;
    const int qw    = qtile * 64 + wg * 16;
    const int qrel  = wg * 16 + r16;
    const int myN   = qtile;            // compute while t <= myN

    const unsigned short* Qp = Qh + ((size_t)bh * S_LEN + qw) * DHEAD;
    bf16x8 qf[2];
#pragma unroll
    for (int d2 = 0; d2 < 2; ++d2)
        qf[d2] = *reinterpret_cast<const bf16x8*>(Qp + (size_t)r16 * DHEAD + d2 * 32 + g * 8);

    auto stageKV = [&](int kt, int buf) {
        gload_lds16((const char*)Kp + (size_t)(kt * 64 + srow) * 128 + sswz,
                    (char*)ldsK[buf] + tid * 16);
        gload_lds16((const char*)Vp + (size_t)srow * (S_LEN * 2) + (size_t)kt * 128 + sswz,
                    (char*)ldsV[buf] + tid * 16);
    };

    float l_run = 0.f;
    f32x4 of[4];
#pragma unroll
    for (int nt = 0; nt < 4; ++nt) of[nt] = (f32x4){0, 0, 0, 0};

    int buf = 0;
    stageKV(0, 0);
    __syncthreads();
    for (int t = 0; t <= qh; ++t) {
        if (t < qh) stageKV(t + 1, buf ^ 1);
        if (t <= myN) {
            const bool masked = (t == myN);
            bf16x8 kf[8];
#pragma unroll
            for (int d2 = 0; d2 < 2; ++d2)
#pragma unroll
                for (int nt = 0; nt < 4; ++nt)
                    kf[d2 * 4 + nt] = *reinterpret_cast<const bf16x8*>(
                        (const char*)ldsK[buf] + (nt * 16 + r16) * 128 + ((d2 * 64 + g * 16) ^ rsw));
            f32x4 sf[4];
#pragma unroll
            for (int nt = 0; nt < 4; ++nt) sf[nt] = (f32x4){0, 0, 0, 0};
            __builtin_amdgcn_s_setprio(1);
#pragma unroll
            for (int d2 = 0; d2 < 2; ++d2)
#pragma unroll
                for (int nt = 0; nt < 4; ++nt)
                    sf[nt] = __builtin_amdgcn_mfma_f32_16x16x32_bf16(kf[d2 * 4 + nt], qf[d2], sf[nt], 0, 0, 0);
            __builtin_amdgcn_s_setprio(0);
            float sum = 0.f;
#pragma unroll
            for (int nt = 0; nt < 4; ++nt)
#pragma unroll
                for (int rr = 0; rr < 4; ++rr) {
                    float e = __builtin_amdgcn_exp2f(sf[nt][rr]);   // unnormalized
                    if (masked && (nt * 16 + g * 4 + rr > qrel)) e = 0.f;
                    sf[nt][rr] = e;
                    sum += e;
                }
            l_run += sum;
#pragma unroll
            for (int nt = 0; nt < 4; ++nt) {
                uint2 pk2;
                pk2.x = cvt_pk_bf16(sf[nt][0], sf[nt][1]);
                pk2.y = cvt_pk_bf16(sf[nt][2], sf[nt][3]);
                *reinterpret_cast<uint2*>(&pl[r16 * 72 + nt * 16 + g * 4]) = pk2;
            }
            __builtin_amdgcn_wave_barrier();
            __builtin_amdgcn_s_setprio(1);
#pragma unroll
            for (int kh = 0; kh < 2; ++kh) {
                bf16x8 pa = *reinterpret_cast<const bf16x8*>(&pl[r16 * 72 + kh * 32 + g * 8]);
#pragma unroll
                for (int nt = 0; nt < 4; ++nt) {
                    bf16x8 vf = *reinterpret_cast<const bf16x8*>(
                        (const char*)ldsV[buf] + (nt * 16 + r16) * 128 + ((kh * 64 + g * 16) ^ rsw));
                    of[nt] = __builtin_amdgcn_mfma_f32_16x16x32_bf16(vf, pa, of[nt], 0, 0, 0);
                }
            }
            __builtin_amdgcn_s_setprio(0);
        }
        __syncthreads();   // publishes buf^1, guards buf overwrite
        buf ^= 1;
    }

    float lx = l_run;
    lx += __shfl_xor(lx, 16);
    lx += __shfl_xor(lx, 32);
    const float mprime = __builtin_amdgcn_logf(lx);   // log2(l)
    if (lane < 16)
        stats[(size_t)bh * S_LEN + qw + r16] = mprime;

    const float inv = 1.f / lx;
    const size_t crow = ((size_t)b * S_LEN + qw + r16) * D_MODEL + h * DHEAD;
#pragma unroll
    for (int nt = 0; nt < 4; ++nt) {
        uint2 pk2;
        pk2.x = cvt_pk_bf16(of[nt][0] * inv, of[nt][1] * inv);
        pk2.y = cvt_pk_bf16(of[nt][2] * inv, of[nt][3] * inv);
        *reinterpret_cast<uint2*>(&ctx[crow + nt * 16 + g * 4]) = pk2;
    }
}

// ---------------- fused output: gemm_o (256) + band-local chunk grid (16384) --
// Chunk (bh, qt, c2): 64 rows x 128 cols at (qt band, cols c2*128). Chunks
// fully above the diagonal are pure-zero stores; others compute P. Every
// block's 64 KB of stores land in its OWN row band (single-region streams).
__global__ __launch_bounds__(256) void fused_out(
    const unsigned short* __restrict__ ctx,
    const unsigned short* __restrict__ wob,
    const float* __restrict__ wo_b,
    float* __restrict__ yout,
    const unsigned short* __restrict__ Qh,
    const unsigned short* __restrict__ Kh,
    const float* __restrict__ stats,
    float* __restrict__ attn_out)
{
    __shared__ unsigned short lds[64 * 136 + 64];   // 17.5 KB (gemm uses 16 KB)
    const int bid = blockIdx.x;
    if (bid < 256) {
        gemm_body<2>(lds, lds + 128 * 32, ctx, wob, wo_b, yout, bid & 7, bid >> 3, 1.0f);
        return;
    }

    const int tid  = threadIdx.x;
    const int lane = tid & 63;
    const int w    = tid >> 6;          // 0..3
    const int g    = lane >> 4, r16 = lane & 15;

    // band-local decode: pid%8 = XCD; each XCD owns 4 bh x 32 qt x 16 c2.
    const int pid = bid - 256;          // 0..16383
    const int xcd = pid & 7;
    const int cid = pid >> 3;           // 0..2047
    const int bh  = xcd * 4 + (cid >> 9);
    const int rem = cid & 511;
    const int qt  = rem >> 4;
    const int c2  = rem & 15;

    const int qw = qt * 64 + w * 16;
    float* dst0 = attn_out + (size_t)bh * S_LEN * S_LEN
                + (size_t)qw * S_LEN + c2 * 128;
    const int rsub = lane >> 5;             // 0..1
    const int cc2  = (lane & 31) * 4;       // 0..124
    const f32x4 z4 = (f32x4){0.f, 0.f, 0.f, 0.f};

    if (2 * c2 > qt) {
        // pure zero chunk: 8 insts x (2 rows x 512B), own band
#pragma unroll
        for (int i = 0; i < 8; ++i)
            __builtin_nontemporal_store(z4,
                reinterpret_cast<f32x4*>(dst0 + (size_t)(i * 2 + rsub) * S_LEN + cc2));
        return;
    }

    // compute chunk: P tiles kt = 2c2, 2c2+1 (masked at/above diagonal)
    const int qrel = w * 16 + r16;
    const unsigned short* Qp = Qh + ((size_t)bh * S_LEN + qw) * DHEAD;
    const unsigned short* Kp = Kh + (size_t)bh * S_LEN * DHEAD;

    bf16x8 qf[2];
#pragma unroll
    for (int d2 = 0; d2 < 2; ++d2)
        qf[d2] = *reinterpret_cast<const bf16x8*>(Qp + (size_t)r16 * DHEAD + d2 * 32 + g * 8);
    const float mpr = stats[(size_t)bh * S_LEN + qw + r16];

    unsigned short* plw = lds + w * (16 * 136);

#pragma unroll
    for (int kl = 0; kl < 2; ++kl) {
        const int kt = 2 * c2 + kl;
        if (kt > qt) {
            const uint2 zz = {0u, 0u};
#pragma unroll
            for (int nt = 0; nt < 4; ++nt)
                *reinterpret_cast<uint2*>(&plw[r16 * 136 + kl * 64 + nt * 16 + g * 4]) = zz;
            continue;
        }
        bf16x8 kf[8];
#pragma unroll
        for (int d2 = 0; d2 < 2; ++d2)
#pragma unroll
            for (int nt = 0; nt < 4; ++nt)
                kf[d2 * 4 + nt] = *reinterpret_cast<const bf16x8*>(
                    Kp + (size_t)(kt * 64 + nt * 16 + r16) * DHEAD + d2 * 32 + g * 8);
        f32x4 sf[4];
#pragma unroll
        for (int nt = 0; nt < 4; ++nt) sf[nt] = (f32x4){0, 0, 0, 0};
        __builtin_amdgcn_s_setprio(1);
#pragma unroll
        for (int d2 = 0; d2 < 2; ++d2)
#pragma unroll
            for (int nt = 0; nt < 4; ++nt)
                sf[nt] = __builtin_amdgcn_mfma_f32_16x16x32_bf16(kf[d2 * 4 + nt], qf[d2], sf[nt], 0, 0, 0);
        __builtin_amdgcn_s_setprio(0);
        const bool masked = (kt == qt);
#pragma unroll
        for (int nt = 0; nt < 4; ++nt) {
#pragma unroll
            for (int rr = 0; rr < 4; ++rr) {
                float p = __builtin_amdgcn_exp2f(sf[nt][rr] - mpr);
                if (masked && (nt * 16 + g * 4 + rr > qrel)) p = 0.f;
                sf[nt][rr] = p;
            }
            uint2 pk2;
            pk2.x = cvt_pk_bf16(sf[nt][0], sf[nt][1]);
            pk2.y = cvt_pk_bf16(sf[nt][2], sf[nt][3]);
            *reinterpret_cast<uint2*>(&plw[r16 * 136 + kl * 64 + nt * 16 + g * 4]) = pk2;
        }
    }
    __builtin_amdgcn_wave_barrier();

    // readback: 8 insts x (2 rows x 512B) = 1 KB contiguous pairs, nt stores
#pragma unroll
    for (int i = 0; i < 8; ++i) {
        const int r = i * 2 + rsub;
        uint2 d = *reinterpret_cast<const uint2*>(&plw[r * 136 + cc2]);
        f32x4 o;
        o[0] = bf2f(d.x & 0xffffu);
        o[1] = bf2f(d.x >> 16);
        o[2] = bf2f(d.y & 0xffffu);
        o[3] = bf2f(d.y >> 16);
        __builtin_nontemporal_store(o, reinterpret_cast<f32x4*>(dst0 + (size_t)r * S_LEN + cc2));
    }
}

extern "C" void kernel_launch(void* const* d_in, const int* in_sizes, int n_in,
                              void* d_out, int out_size, void* d_ws, size_t ws_size,
                              hipStream_t stream)
{
    const float* q    = (const float*)d_in[0];
    const float* k    = (const float*)d_in[1];
    const float* v    = (const float*)d_in[2];
    const float* wq_w = (const float*)d_in[4];
    const float* wq_b = (const float*)d_in[5];
    const float* wk_w = (const float*)d_in[6];
    const float* wk_b = (const float*)d_in[7];
    const float* wv_w = (const float*)d_in[8];
    const float* wv_b = (const float*)d_in[9];
    const float* wo_w = (const float*)d_in[10];
    const float* wo_b = (const float*)d_in[11];

    char* ws = (char*)d_ws;
    const size_t MB = 1024 * 1024;
    unsigned short* qb  = (unsigned short*)(ws + 0 * MB);
    unsigned short* kb  = (unsigned short*)(ws + 8 * MB);
    unsigned short* vb  = (unsigned short*)(ws + 16 * MB);
    unsigned short* wqb = (unsigned short*)(ws + 24 * MB);
    unsigned short* wkb = (unsigned short*)(ws + 26 * MB);
    unsigned short* wvb = (unsigned short*)(ws + 28 * MB);
    unsigned short* wob = (unsigned short*)(ws + 30 * MB);
    unsigned short* Qhp = (unsigned short*)(ws + 32 * MB);
    unsigned short* Khp = (unsigned short*)(ws + 40 * MB);
    unsigned short* Vtp = (unsigned short*)(ws + 48 * MB);
    unsigned short* ctx = (unsigned short*)(ws + 56 * MB);
    // stats overlays qb (dead after projections; rewritten every launch)
    float* stats = (float*)(ws + 0 * MB);

    float* yout = (float*)d_out;
    float* attn = yout + (size_t)M_ROWS * D_MODEL;

    CvtArgs ca;
    ca.src[0] = q;    ca.dst[0] = qb;  ca.n4[0] = M_ROWS * D_MODEL / 4;
    ca.src[1] = k;    ca.dst[1] = kb;  ca.n4[1] = M_ROWS * D_MODEL / 4;
    ca.src[2] = v;    ca.dst[2] = vb;  ca.n4[2] = M_ROWS * D_MODEL / 4;
    ca.src[3] = wq_w; ca.dst[3] = wqb; ca.n4[3] = D_MODEL * D_MODEL / 4;
    ca.src[4] = wk_w; ca.dst[4] = wkb; ca.n4[4] = D_MODEL * D_MODEL / 4;
    ca.src[5] = wv_w; ca.dst[5] = wvb; ca.n4[5] = D_MODEL * D_MODEL / 4;
    ca.src[6] = wo_w; ca.dst[6] = wob; ca.n4[6] = D_MODEL * D_MODEL / 4;
    cvt_all<<<dim3((M_ROWS * D_MODEL / 4 + 255) / 256, 7), dim3(256), 0, stream>>>(ca);

    const float qscale = 0.125f * 1.44269504088896340736f;  // fold scale*log2(e) into Q
    proj_all<<<dim3(768), dim3(256), 0, stream>>>(
        qb, wqb, wq_b, Qhp,
        kb, wkb, wk_b, Khp,
        vb, wvb, wv_b, Vtp, qscale);

    attn_ctx_kernel<<<dim3(512), dim3(512), 0, stream>>>(Qhp, Khp, Vtp, stats, ctx);

    fused_out<<<dim3(256 + 16384), dim3(256), 0, stream>>>(
        ctx, wob, wo_b, yout, Qhp, Khp, stats, attn);
}